// Round 3
// baseline (79.777 us; speedup 1.0000x reference)
//
#include <hip/hip_runtime.h>
#include <math.h>

#define Cc 512
#define Pp 1024
#define NROW 25088      // B*N = 8*3136
#define BM 128          // rows per block
#define BNP 128         // centroid cols per block (P-split: 8 pblocks)
#define BK 32

typedef short  bf16x8 __attribute__((ext_vector_type(8)));   // 8 bf16 = 4 VGPR
typedef float  f32x4  __attribute__((ext_vector_type(4)));
typedef unsigned short u16x8 __attribute__((ext_vector_type(8)));

__device__ __forceinline__ unsigned short bf16_rne(float f) {
    unsigned int u = __float_as_uint(f);
    return (unsigned short)((u + 0x7fffu + ((u >> 16) & 1u)) >> 16);
}

// ---------------------------------------------------------------------------
// Fused fp32 -> bf16 (RNE) conversion + row squared-norm. One wave per row.
// ---------------------------------------------------------------------------
__global__ __launch_bounds__(256) void conv_norm_kernel(
        const float* __restrict__ src, unsigned short* __restrict__ dst,
        float* __restrict__ nrm) {
    int wid  = blockIdx.x * 4 + (threadIdx.x >> 6);
    int lane = threadIdx.x & 63;
    const float4* r = (const float4*)(src + (size_t)wid * Cc);
    float4 a = r[lane * 2];
    float4 b = r[lane * 2 + 1];
    u16x8 o;
    o[0] = bf16_rne(a.x); o[1] = bf16_rne(a.y); o[2] = bf16_rne(a.z); o[3] = bf16_rne(a.w);
    o[4] = bf16_rne(b.x); o[5] = bf16_rne(b.y); o[6] = bf16_rne(b.z); o[7] = bf16_rne(b.w);
    *(u16x8*)(dst + (size_t)wid * Cc + lane * 8) = o;
    float s = a.x*a.x + a.y*a.y + a.z*a.z + a.w*a.w
            + b.x*b.x + b.y*b.y + b.z*b.z + b.w*b.w;
    #pragma unroll
    for (int m = 1; m < 64; m <<= 1) s += __shfl_xor(s, m);
    if (lane == 0) nrm[wid] = s;
}

// branch-free sorted insert of v into (t0 <= t1 <= t2), keeping smallest 3
#define TOP3_INSERT(t0, t1, t2, v)                                  \
    do {                                                            \
        float _n0 = fminf((t0), (v));                               \
        float _h0 = fmaxf((t0), (v));                               \
        float _n1 = fminf((t1), _h0);                               \
        float _h1 = fmaxf((t1), _h0);                               \
        float _n2 = fminf((t2), _h1);                               \
        (t0) = _n0; (t1) = _n1; (t2) = _n2;                         \
    } while (0)

#define GLOAD_LDS16(gp, lp)                                             \
    __builtin_amdgcn_global_load_lds(                                   \
        (const __attribute__((address_space(1))) void*)(const void*)(gp),\
        (__attribute__((address_space(3))) void*)(void*)(lp), 16, 0, 0)

// ---------------------------------------------------------------------------
// Main: m97-structure 128x128 bf16 MFMA tile, fused per-P-block top-3.
// Grid: (25088/128) * 8 pblocks = 1568 blocks, 256 threads = 4 waves (2x2).
// Wave tile 64x64 = 4x4 fragments of 16x16x32; BK=32; 16 K-steps.
// Stores per-row top3 of (cnorm - 2*dot) for this pblock (fnorm added later).
// ---------------------------------------------------------------------------
__global__ __launch_bounds__(256) void mfma_topk_kernel(
        const unsigned short* __restrict__ Eb, const unsigned short* __restrict__ Cb,
        const float* __restrict__ cnorm, float* __restrict__ wsTop) {
    __shared__ unsigned short As[BM * BK];    // 8 KB
    __shared__ unsigned short Bs[BNP * BK];   // 8 KB
    __shared__ float tops[2][BM][3];          // 3 KB, [wn][row_local][k]

    const int tid    = threadIdx.x;
    const int lane   = tid & 63;
    const int w      = tid >> 6;
    const int wm     = w >> 1;       // 0..1 row half
    const int wn     = w & 1;        // 0..1 col half
    const int g      = lane >> 4;    // 0..3
    const int q      = lane & 15;    // 0..15
    const int mblock = blockIdx.x >> 3;
    const int pblock = blockIdx.x & 7;
    const int row0   = mblock * BM;
    const int p0     = pblock * BNP;

    f32x4 acc[4][4];
    #pragma unroll
    for (int m = 0; m < 4; ++m)
        #pragma unroll
        for (int n = 0; n < 4; ++n) acc[m][n] = (f32x4){0.f, 0.f, 0.f, 0.f};

    // staging chunk ids (16B chunks; 512 for A, 512 for B; 256 threads)
    const int c0 = tid, c1 = tid + 256;

    for (int kk = 0; kk < Cc; kk += BK) {
        __syncthreads();    // previous tile's reads done
        GLOAD_LDS16(Eb + (size_t)(row0 + (c0 >> 2)) * Cc + kk + (c0 & 3) * 8,
                    (char*)As + c0 * 16);
        GLOAD_LDS16(Eb + (size_t)(row0 + (c1 >> 2)) * Cc + kk + (c1 & 3) * 8,
                    (char*)As + c1 * 16);
        GLOAD_LDS16(Cb + (size_t)(p0 + (c0 >> 2)) * Cc + kk + (c0 & 3) * 8,
                    (char*)Bs + c0 * 16);
        GLOAD_LDS16(Cb + (size_t)(p0 + (c1 >> 2)) * Cc + kk + (c1 & 3) * 8,
                    (char*)Bs + c1 * 16);
        __syncthreads();    // staging complete (drains vmcnt)

        bf16x8 a[4], b[4];
        #pragma unroll
        for (int m = 0; m < 4; ++m)
            a[m] = *(const bf16x8*)(As + (wm * 64 + m * 16 + q) * BK + g * 8);
        #pragma unroll
        for (int n = 0; n < 4; ++n)
            b[n] = *(const bf16x8*)(Bs + (wn * 64 + n * 16 + q) * BK + g * 8);
        #pragma unroll
        for (int m = 0; m < 4; ++m)
            #pragma unroll
            for (int n = 0; n < 4; ++n)
                acc[m][n] = __builtin_amdgcn_mfma_f32_16x16x32_bf16(
                    a[m], b[n], acc[m][n], 0, 0, 0);
    }

    // ---- epilogue: v = cn - 2*dot ; per-row top3 within this pblock ----
    float cn[4];
    #pragma unroll
    for (int n = 0; n < 4; ++n) cn[n] = cnorm[p0 + wn * 64 + n * 16 + q];

    #pragma unroll
    for (int m = 0; m < 4; ++m) {
        float u0[4], u1[4], u2[4];
        #pragma unroll
        for (int r = 0; r < 4; ++r) { u0[r] = 1e30f; u1[r] = 1e30f; u2[r] = 1e30f; }
        #pragma unroll
        for (int n = 0; n < 4; ++n)
            #pragma unroll
            for (int r = 0; r < 4; ++r) {
                float v = cn[n] - 2.f * acc[m][n][r];
                TOP3_INSERT(u0[r], u1[r], u2[r], v);
            }
        // merge across the 16 q-lanes (same rows, different cols)
        #pragma unroll
        for (int mask = 1; mask <= 8; mask <<= 1) {
            #pragma unroll
            for (int r = 0; r < 4; ++r) {
                float o0 = __shfl_xor(u0[r], mask);
                float o1 = __shfl_xor(u1[r], mask);
                float o2 = __shfl_xor(u2[r], mask);
                TOP3_INSERT(u0[r], u1[r], u2[r], o0);
                TOP3_INSERT(u0[r], u1[r], u2[r], o1);
                TOP3_INSERT(u0[r], u1[r], u2[r], o2);
            }
        }
        if (q == 0) {
            #pragma unroll
            for (int r = 0; r < 4; ++r) {
                int rl = wm * 64 + m * 16 + g * 4 + r;
                tops[wn][rl][0] = u0[r];
                tops[wn][rl][1] = u1[r];
                tops[wn][rl][2] = u2[r];
            }
        }
    }
    __syncthreads();

    if (tid < BM) {
        float a0 = tops[0][tid][0], a1 = tops[0][tid][1], a2 = tops[0][tid][2];
        TOP3_INSERT(a0, a1, a2, tops[1][tid][0]);
        TOP3_INSERT(a0, a1, a2, tops[1][tid][1]);
        TOP3_INSERT(a0, a1, a2, tops[1][tid][2]);
        float* dst = wsTop + (size_t)(row0 + tid) * 24 + pblock * 3;
        dst[0] = a0; dst[1] = a1; dst[2] = a2;
    }
}

// ---------------------------------------------------------------------------
// Final merge: fold 8 pblocks' top3, add row norm, sqrt + softmin, store.
// ---------------------------------------------------------------------------
__global__ __launch_bounds__(256) void merge_kernel(
        const float* __restrict__ wsTop, const float* __restrict__ fnorm,
        float* __restrict__ out) {
    int r = blockIdx.x * 256 + threadIdx.x;      // 25088 = 98*256 exact
    const float* p = wsTop + (size_t)r * 24;
    float t0 = p[0], t1 = p[1], t2 = p[2];
    #pragma unroll
    for (int pb = 1; pb < 8; ++pb) {
        TOP3_INSERT(t0, t1, t2, p[pb * 3 + 0]);
        TOP3_INSERT(t0, t1, t2, p[pb * 3 + 1]);
        TOP3_INSERT(t0, t1, t2, p[pb * 3 + 2]);
    }
    float fn = fnorm[r];
    float d0 = sqrtf(fmaxf(fn + t0, 0.f));
    float d1 = sqrtf(fmaxf(fn + t1, 0.f));
    float d2 = sqrtf(fmaxf(fn + t2, 0.f));
    float w0 = 1.f / (1.f + __expf(d0 - d1) + __expf(d0 - d2));
    out[r] = w0 * d0;
}

extern "C" void kernel_launch(void* const* d_in, const int* in_sizes, int n_in,
                              void* d_out, int out_size, void* d_ws, size_t ws_size,
                              hipStream_t stream) {
    (void)in_sizes; (void)n_in; (void)out_size; (void)ws_size;
    const float* embeds    = (const float*)d_in[0];   // [8,3136,512] fp32
    const float* centroids = (const float*)d_in[1];   // [1024,512]  fp32
    float* out = (float*)d_out;

    // ws layout (bytes):
    //   cnorm  @ 0         (4 KB)
    //   fnorm  @ 4096      (100,352 B)
    //   wsTop  @ 104448    (25088*8*3*4 = 2,408,448 B)  [row][pblock][3]
    //   Eb     @ 2512896   (25,690,112 B bf16)
    //   Cb     @ 28203008  (1,048,576 B bf16)           total ~27.9 MB
    char* ws = (char*)d_ws;
    float*          cnorm = (float*)(ws);
    float*          fnorm = (float*)(ws + 4096);
    float*          wsTop = (float*)(ws + 104448);
    unsigned short* Eb    = (unsigned short*)(ws + 2512896);
    unsigned short* Cb    = (unsigned short*)(ws + 28203008);

    conv_norm_kernel<<<NROW / 4, 256, 0, stream>>>(embeds, Eb, fnorm);
    conv_norm_kernel<<<Pp / 4,   256, 0, stream>>>(centroids, Cb, cnorm);
    mfma_topk_kernel<<<(NROW / BM) * 8, 256, 0, stream>>>(Eb, Cb, cnorm, wsTop);
    merge_kernel<<<NROW / 256, 256, 0, stream>>>(wsTop, fnorm, out);
}

// Round 4
// 72.914 us; speedup vs baseline: 1.0941x; 1.0941x over previous
//
#include <hip/hip_runtime.h>
#include <math.h>

#define Cc 512
#define Pp 1024
#define NROW 25088      // B*N = 8*3136
#define BM 128          // rows per block
#define BNP 128         // centroid cols per block (8 pblocks)
#define BK 64           // K tile (8 K-steps)
#define NMB 196         // real mblocks = 25088/128
#define NMB_PAD 200     // padded so mblocks group 8-per-XCD

typedef short  bf16x8 __attribute__((ext_vector_type(8)));   // 8 bf16 = 4 VGPR
typedef float  f32x4  __attribute__((ext_vector_type(4)));
typedef unsigned short u16x8 __attribute__((ext_vector_type(8)));

__device__ __forceinline__ unsigned short bf16_rne(float f) {
    unsigned int u = __float_as_uint(f);
    return (unsigned short)((u + 0x7fffu + ((u >> 16) & 1u)) >> 16);
}

// ---------------------------------------------------------------------------
// Fused fp32 -> bf16 (RNE) conversion + row squared-norm. One wave per row.
// ---------------------------------------------------------------------------
__global__ __launch_bounds__(256) void conv_norm_kernel(
        const float* __restrict__ src, unsigned short* __restrict__ dst,
        float* __restrict__ nrm) {
    int wid  = blockIdx.x * 4 + (threadIdx.x >> 6);
    int lane = threadIdx.x & 63;
    const float4* r = (const float4*)(src + (size_t)wid * Cc);
    float4 a = r[lane * 2];
    float4 b = r[lane * 2 + 1];
    u16x8 o;
    o[0] = bf16_rne(a.x); o[1] = bf16_rne(a.y); o[2] = bf16_rne(a.z); o[3] = bf16_rne(a.w);
    o[4] = bf16_rne(b.x); o[5] = bf16_rne(b.y); o[6] = bf16_rne(b.z); o[7] = bf16_rne(b.w);
    *(u16x8*)(dst + (size_t)wid * Cc + lane * 8) = o;
    float s = a.x*a.x + a.y*a.y + a.z*a.z + a.w*a.w
            + b.x*b.x + b.y*b.y + b.z*b.z + b.w*b.w;
    #pragma unroll
    for (int m = 1; m < 64; m <<= 1) s += __shfl_xor(s, m);
    if (lane == 0) nrm[wid] = s;
}

// branch-free sorted insert of v into (t0 <= t1 <= t2), keeping smallest 3
#define TOP3_INSERT(t0, t1, t2, v)                                  \
    do {                                                            \
        float _n0 = fminf((t0), (v));                               \
        float _h0 = fmaxf((t0), (v));                               \
        float _n1 = fminf((t1), _h0);                               \
        float _h1 = fmaxf((t1), _h0);                               \
        float _n2 = fminf((t2), _h1);                               \
        (t0) = _n0; (t1) = _n1; (t2) = _n2;                         \
    } while (0)

#define GLOAD_LDS16(gp, lp)                                             \
    __builtin_amdgcn_global_load_lds(                                   \
        (const __attribute__((address_space(1))) void*)(const void*)(gp),\
        (__attribute__((address_space(3))) void*)(void*)(lp), 16, 0, 0)

// ---------------------------------------------------------------------------
// Main: 128x128 bf16 MFMA tile, BK=64, XOR-swizzled LDS (T2, both-sides),
// XCD-grouped P-split (T1 variant), fused per-P-block top-3.
// Grid: 1600 blocks (200 padded mblocks x 8 pblocks), 256 thr = 4 waves 2x2.
// Wave tile 64x64 = 4x4 fragments, 2 k-substeps -> 32 MFMA per K-step.
// ---------------------------------------------------------------------------
__global__ __launch_bounds__(256, 4) void mfma_topk_kernel(
        const unsigned short* __restrict__ Eb, const unsigned short* __restrict__ Cb,
        const float* __restrict__ cnorm, float* __restrict__ wsTop) {
    // XCD-grouped decode: all 8 pblocks of an mblock land on one XCD
    const int xcd = blockIdx.x & 7;
    const int t   = blockIdx.x >> 3;          // 0..199
    const int mblock = ((t >> 3) << 3) | xcd; // 0..199
    const int pblock = t & 7;
    if (mblock >= NMB) return;                // uniform early-exit (no barriers yet)

    __shared__ unsigned short As[BM * BK];    // 16 KB
    __shared__ unsigned short Bs[BNP * BK];   // 16 KB
    __shared__ float tops[2][BM][3];          // 3 KB

    const int tid  = threadIdx.x;
    const int lane = tid & 63;
    const int w    = tid >> 6;
    const int wm   = w >> 1;       // 0..1 row half
    const int wn   = w & 1;        // 0..1 col half
    const int g    = lane >> 4;    // 0..3
    const int q    = lane & 15;    // 0..15
    const int qa   = q & 7;        // row&7 for swizzle (rows are q mod 16-aligned)
    const int row0 = mblock * BM;
    const int p0   = pblock * BNP;

    f32x4 acc[4][4];
    #pragma unroll
    for (int m = 0; m < 4; ++m)
        #pragma unroll
        for (int n = 0; n < 4; ++n) acc[m][n] = (f32x4){0.f, 0.f, 0.f, 0.f};

    // K loop: 8 steps of BK=64. Staging: 1024 16B-chunks each for A and B.
    // chunk c: row = c>>3, slot = c&7; LDS dest linear (c*16); global source
    // pre-swizzled: sg = slot ^ (row&7)  (involution; reader applies same XOR)
    for (int kk = 0; kk < Cc; kk += BK) {
        __syncthreads();    // previous step's LDS reads done
        #pragma unroll
        for (int it = 0; it < 4; ++it) {
            int c = tid + it * 256;
            int row = c >> 3;
            int sg  = (c & 7) ^ (row & 7);
            GLOAD_LDS16(Eb + (size_t)(row0 + row) * Cc + kk + sg * 8,
                        (char*)As + c * 16);
        }
        #pragma unroll
        for (int it = 0; it < 4; ++it) {
            int c = tid + it * 256;
            int row = c >> 3;
            int sg  = (c & 7) ^ (row & 7);
            GLOAD_LDS16(Cb + (size_t)(p0 + row) * Cc + kk + sg * 8,
                        (char*)Bs + c * 16);
        }
        __syncthreads();    // staging complete (vmcnt drained by compiler)

        #pragma unroll
        for (int ks = 0; ks < 2; ++ks) {
            const int slot = ((ks << 2) | g) ^ qa;   // swizzled 16B slot
            bf16x8 a[4], b[4];
            #pragma unroll
            for (int m = 0; m < 4; ++m)
                a[m] = *(const bf16x8*)((const char*)As +
                        (wm * 64 + m * 16 + q) * 128 + slot * 16);
            #pragma unroll
            for (int n = 0; n < 4; ++n)
                b[n] = *(const bf16x8*)((const char*)Bs +
                        (wn * 64 + n * 16 + q) * 128 + slot * 16);
            #pragma unroll
            for (int m = 0; m < 4; ++m)
                #pragma unroll
                for (int n = 0; n < 4; ++n)
                    acc[m][n] = __builtin_amdgcn_mfma_f32_16x16x32_bf16(
                        a[m], b[n], acc[m][n], 0, 0, 0);
        }
    }

    // ---- epilogue: v = cn - 2*dot ; per-row top3 within this pblock ----
    float cn[4];
    #pragma unroll
    for (int n = 0; n < 4; ++n) cn[n] = cnorm[p0 + wn * 64 + n * 16 + q];

    #pragma unroll
    for (int m = 0; m < 4; ++m) {
        float u0[4], u1[4], u2[4];
        #pragma unroll
        for (int r = 0; r < 4; ++r) { u0[r] = 1e30f; u1[r] = 1e30f; u2[r] = 1e30f; }
        #pragma unroll
        for (int n = 0; n < 4; ++n)
            #pragma unroll
            for (int r = 0; r < 4; ++r) {
                float v = cn[n] - 2.f * acc[m][n][r];
                TOP3_INSERT(u0[r], u1[r], u2[r], v);
            }
        // merge across the 16 q-lanes (same rows, different cols)
        #pragma unroll
        for (int mask = 1; mask <= 8; mask <<= 1) {
            #pragma unroll
            for (int r = 0; r < 4; ++r) {
                float o0 = __shfl_xor(u0[r], mask);
                float o1 = __shfl_xor(u1[r], mask);
                float o2 = __shfl_xor(u2[r], mask);
                TOP3_INSERT(u0[r], u1[r], u2[r], o0);
                TOP3_INSERT(u0[r], u1[r], u2[r], o1);
                TOP3_INSERT(u0[r], u1[r], u2[r], o2);
            }
        }
        if (q == 0) {
            #pragma unroll
            for (int r = 0; r < 4; ++r) {
                int rl = wm * 64 + m * 16 + g * 4 + r;
                tops[wn][rl][0] = u0[r];
                tops[wn][rl][1] = u1[r];
                tops[wn][rl][2] = u2[r];
            }
        }
    }
    __syncthreads();

    if (tid < BM) {
        float a0 = tops[0][tid][0], a1 = tops[0][tid][1], a2 = tops[0][tid][2];
        TOP3_INSERT(a0, a1, a2, tops[1][tid][0]);
        TOP3_INSERT(a0, a1, a2, tops[1][tid][1]);
        TOP3_INSERT(a0, a1, a2, tops[1][tid][2]);
        float* dst = wsTop + (size_t)(row0 + tid) * 24 + pblock * 3;
        dst[0] = a0; dst[1] = a1; dst[2] = a2;
    }
}

// ---------------------------------------------------------------------------
// Final merge: fold 8 pblocks' top3, add row norm, sqrt + softmin, store.
// ---------------------------------------------------------------------------
__global__ __launch_bounds__(256) void merge_kernel(
        const float* __restrict__ wsTop, const float* __restrict__ fnorm,
        float* __restrict__ out) {
    int r = blockIdx.x * 256 + threadIdx.x;      // 25088 = 98*256 exact
    const float* p = wsTop + (size_t)r * 24;
    float t0 = p[0], t1 = p[1], t2 = p[2];
    #pragma unroll
    for (int pb = 1; pb < 8; ++pb) {
        TOP3_INSERT(t0, t1, t2, p[pb * 3 + 0]);
        TOP3_INSERT(t0, t1, t2, p[pb * 3 + 1]);
        TOP3_INSERT(t0, t1, t2, p[pb * 3 + 2]);
    }
    float fn = fnorm[r];
    float d0 = sqrtf(fmaxf(fn + t0, 0.f));
    float d1 = sqrtf(fmaxf(fn + t1, 0.f));
    float d2 = sqrtf(fmaxf(fn + t2, 0.f));
    float w0 = 1.f / (1.f + __expf(d0 - d1) + __expf(d0 - d2));
    out[r] = w0 * d0;
}

extern "C" void kernel_launch(void* const* d_in, const int* in_sizes, int n_in,
                              void* d_out, int out_size, void* d_ws, size_t ws_size,
                              hipStream_t stream) {
    (void)in_sizes; (void)n_in; (void)out_size; (void)ws_size;
    const float* embeds    = (const float*)d_in[0];   // [8,3136,512] fp32
    const float* centroids = (const float*)d_in[1];   // [1024,512]  fp32
    float* out = (float*)d_out;

    // ws layout (bytes):
    //   cnorm  @ 0         (4 KB)
    //   fnorm  @ 4096      (100,352 B)
    //   wsTop  @ 104448    (25088*8*3*4 = 2,408,448 B)  [row][pblock][3]
    //   Eb     @ 2512896   (25,690,112 B bf16)
    //   Cb     @ 28203008  (1,048,576 B bf16)           total ~27.9 MB
    char* ws = (char*)d_ws;
    float*          cnorm = (float*)(ws);
    float*          fnorm = (float*)(ws + 4096);
    float*          wsTop = (float*)(ws + 104448);
    unsigned short* Eb    = (unsigned short*)(ws + 2512896);
    unsigned short* Cb    = (unsigned short*)(ws + 28203008);

    conv_norm_kernel<<<NROW / 4, 256, 0, stream>>>(embeds, Eb, fnorm);
    conv_norm_kernel<<<Pp / 4,   256, 0, stream>>>(centroids, Cb, cnorm);
    mfma_topk_kernel<<<NMB_PAD * 8, 256, 0, stream>>>(Eb, Cb, cnorm, wsTop);
    merge_kernel<<<NROW / 256, 256, 0, stream>>>(wsTop, fnorm, out);
}